// Round 5
// baseline (18.082 us; speedup 1.0000x reference)
//
#include <hip/hip_runtime.h>

#define B_    4
#define N_    256
#define C_    256
#define OUTN  7
#define NBIN  49          // 7x7 bins
#define C4    64          // float4 groups per pixel (1 KiB per pixel)

typedef float f32x4 __attribute__((ext_vector_type(4)));

// 512 thr/block (8 waves), 1 block/box. lane = c4 channel group; wave wv
// handles bins wv, wv+8, ... (<=7). Each wave computes its own bin params
// redundantly -> NO LDS, NO barrier; fully unrolled loop lets the compiler
// hoist all 28 gather addresses and pipeline loads across blends.
__global__ __launch_bounds__(512) void roi_pool_kernel(
    const float* __restrict__ f0, const float* __restrict__ f1,
    const float* __restrict__ f2, const float* __restrict__ f3,
    const float* __restrict__ f4, const float* __restrict__ boxes,
    float* __restrict__ out)
{
    // ---- XCD-aware block->box swizzle (R2 win: per-XCD L2 locality) ----
    const int i_   = blockIdx.x;
    const int xcd  = i_ & 7;
    const int j_   = i_ >> 3;
    const int bid  = (xcd >> 1) * N_ + (xcd & 1) * 128 + j_;   // b*N + n
    const int b    = bid >> 8;
    const int tid  = threadIdx.x;
    const int lane = tid & 63;
    const int wv   = tid >> 6;

    // ---- per-box scalar params (redundant per thread; off critical path) ----
    const float* bx = boxes + (size_t)bid * 4;
    const float y1 = bx[0], x1 = bx[1], y2 = bx[2], x2 = bx[3];
    const float bh = y2 - y1, bw = x2 - x1;
    const float area_sqrt = sqrtf(bh * bw);
    const float lvf = floorf(logf(area_sqrt / 224.0f) / logf(2.0f)) + 4.0f;
    int levels = (int)lvf;
    levels = min(max(levels, 4), 64);
    const int   lvl    = levels - 4;
    const float scale  = exp2f((float)levels);
    const float stride = exp2f((float)lvl);
    const float bnd    = 128.0f / stride - 1.0f;
    const float box_y  = y1 / scale - 0.5f;
    const float box_x  = x1 / scale - 0.5f;
    const float bh_s   = bh / scale;
    const float bw_s   = bw / scale;

    // ---- feature level (jnp gather clamps level index to [0,4]) ----
    const int lg = lvl > 4 ? 4 : lvl;
    const float* feat; int fs;
    switch (lg) {
        case 0:  feat = f0; fs = 128; break;
        case 1:  feat = f1; fs = 64;  break;
        case 2:  feat = f2; fs = 32;  break;
        case 3:  feat = f3; fs = 16;  break;
        default: feat = f4; fs = 8;   break;
    }

    const char* fbB  = (const char*)feat + (size_t)b * fs * fs * 1024;
    char*       obB  = (char*)out + (size_t)bid * (NBIN * 1024);
    const unsigned laneB = (unsigned)lane << 4;

    #pragma unroll
    for (int i = 0; i < 7; ++i) {
        const int bin = wv + (i << 3);
        if (bin < NBIN) {
            const int oy = bin / 7;               // constant-folded after unroll? wv runtime -> magic mul, once per iter, off loop path
            const int ox = bin - oy * 7;
            const float gy = box_y + (((float)oy + 0.5f) * (1.0f / 7.0f)) * bh_s;
            const float gx = box_x + (((float)ox + 0.5f) * (1.0f / 7.0f)) * bw_s;
            const float py = fmaxf(0.0f, floorf(gy));
            const float px = fmaxf(0.0f, floorf(gx));
            const float ly = gy - py, lx = gx - px;   // ref semantics: l from un-bounded floor
            const float hy = 1.0f - ly, hx = 1.0f - lx;
            const unsigned yb0 = (unsigned)((int)fminf(py,        bnd) * fs) << 10;
            const unsigned yb1 = (unsigned)((int)fminf(py + 1.0f, bnd) * fs) << 10;
            const unsigned xb0 = (unsigned)(int)fminf(px,        bnd) << 10;
            const unsigned xb1 = (unsigned)(int)fminf(px + 1.0f, bnd) << 10;

            const f32x4 f00 = *(const f32x4*)(fbB + (yb0 + xb0 + laneB));
            const f32x4 f01 = *(const f32x4*)(fbB + (yb0 + xb1 + laneB));
            const f32x4 f10 = *(const f32x4*)(fbB + (yb1 + xb0 + laneB));
            const f32x4 f11 = *(const f32x4*)(fbB + (yb1 + xb1 + laneB));

            const float w00 = hy * hx, w01 = hy * lx;
            const float w10 = ly * hx, w11 = ly * lx;
            f32x4 o = w00 * f00 + w01 * f01 + w10 * f10 + w11 * f11;
            // plain store this round (A/B vs R4's nontemporal store)
            *(f32x4*)(obB + (((unsigned)bin << 10) + laneB)) = o;
        }
    }
}

extern "C" void kernel_launch(void* const* d_in, const int* in_sizes, int n_in,
                              void* d_out, int out_size, void* d_ws, size_t ws_size,
                              hipStream_t stream) {
    const float* f0    = (const float*)d_in[0];
    const float* f1    = (const float*)d_in[1];
    const float* f2    = (const float*)d_in[2];
    const float* f3    = (const float*)d_in[3];
    const float* f4    = (const float*)d_in[4];
    const float* boxes = (const float*)d_in[5];
    float*       outp  = (float*)d_out;

    roi_pool_kernel<<<B_ * N_, 512, 0, stream>>>(f0, f1, f2, f3, f4, boxes, outp);
}

// Round 6
// 16.014 us; speedup vs baseline: 1.1292x; 1.1292x over previous
//
#include <hip/hip_runtime.h>

#define B_    4
#define N_    256
#define C_    256
#define OUTN  7
#define NBIN  49          // 7x7 bins
#define C4    64          // float4 groups per pixel (1 KiB per pixel)

typedef float f32x4 __attribute__((ext_vector_type(4)));

struct __align__(16) BinInfo {
    float    w00, w01, w10, w11;   // bilinear weights
    unsigned yb0, yb1, xb0, xb1;   // byte offsets: row0/row1, col0/col1
};

// 512 thr/block (8 waves), 1 block/box, 4 blocks/CU = 32 waves/CU.
// lane = c4 channel group. Wave wv owns the CONTIGUOUS bin chunk
// [49wv/8, 49(wv+1)/8) — 6-7 consecutive bins, mostly within one bin-row,
// so consecutive iterations re-touch the same feature rows and adjacent
// columns -> L1 temporal/spatial hits cut the L2/L3 gather stream.
__global__ __launch_bounds__(512) void roi_pool_kernel(
    const float* __restrict__ f0, const float* __restrict__ f1,
    const float* __restrict__ f2, const float* __restrict__ f3,
    const float* __restrict__ f4, const float* __restrict__ boxes,
    float* __restrict__ out)
{
    // ---- XCD-aware block->box swizzle (R2 win: one batch image per XCD) ----
    const int i_   = blockIdx.x;
    const int xcd  = i_ & 7;
    const int j_   = i_ >> 3;
    const int bid  = (xcd >> 1) * N_ + (xcd & 1) * 128 + j_;   // b*N + n
    const int b    = bid >> 8;
    const int tid  = threadIdx.x;
    const int lane = tid & 63;
    const int wv   = tid >> 6;

    // ---- per-box scalar params ----
    const float* bx = boxes + (size_t)bid * 4;
    const float y1 = bx[0], x1 = bx[1], y2 = bx[2], x2 = bx[3];
    const float bh = y2 - y1, bw = x2 - x1;
    const float area_sqrt = sqrtf(bh * bw);
    const float lvf = floorf(logf(area_sqrt / 224.0f) / logf(2.0f)) + 4.0f;
    int levels = (int)lvf;
    levels = min(max(levels, 4), 64);
    const int   lvl    = levels - 4;
    const float scale  = exp2f((float)levels);
    const float stride = exp2f((float)lvl);
    const float bnd    = 128.0f / stride - 1.0f;
    const float box_y  = y1 / scale - 0.5f;
    const float box_x  = x1 / scale - 0.5f;
    const float bh_s   = bh / scale;
    const float bw_s   = bw / scale;

    // ---- feature level (jnp gather clamps level index to [0,4]) ----
    const int lg = lvl > 4 ? 4 : lvl;
    const float* feat; int fs;
    switch (lg) {
        case 0:  feat = f0; fs = 128; break;
        case 1:  feat = f1; fs = 64;  break;
        case 2:  feat = f2; fs = 32;  break;
        case 3:  feat = f3; fs = 16;  break;
        default: feat = f4; fs = 8;   break;
    }

    // ---- per-bin params: 4 weights + 4 byte offsets, staged in LDS ----
    __shared__ BinInfo sbin[NBIN];
    if (tid < NBIN) {
        const int oy = tid / 7;
        const int ox = tid - oy * 7;
        const float gy = box_y + (((float)oy + 0.5f) * (1.0f / 7.0f)) * bh_s;
        const float gx = box_x + (((float)ox + 0.5f) * (1.0f / 7.0f)) * bw_s;
        const float py = fmaxf(0.0f, floorf(gy));
        const float px = fmaxf(0.0f, floorf(gx));
        const float ly = gy - py, lx = gx - px;   // may be <0/>1 at edges (ref semantics)
        const float hy = 1.0f - ly, hx = 1.0f - lx;
        const int y0  = (int)fminf(py,        bnd);
        const int y1i = (int)fminf(py + 1.0f, bnd);
        const int x0  = (int)fminf(px,        bnd);
        const int x1i = (int)fminf(px + 1.0f, bnd);
        BinInfo bi;
        bi.w00 = hy * hx; bi.w01 = hy * lx;
        bi.w10 = ly * hx; bi.w11 = ly * lx;
        bi.yb0 = (unsigned)(y0  * fs) << 10;      // row byte offset (fs px * 1KiB)
        bi.yb1 = (unsigned)(y1i * fs) << 10;
        bi.xb0 = (unsigned)x0 << 10;              // col byte offset
        bi.xb1 = (unsigned)x1i << 10;
        sbin[tid] = bi;
    }
    __syncthreads();

    // uniform 64-bit bases; all per-corner addressing is 32-bit offsets
    const char* fbB  = (const char*)feat + (size_t)b * fs * fs * 1024;
    char*       obB  = (char*)out + (size_t)bid * (NBIN * 1024);
    const unsigned laneB = (unsigned)lane << 4;

    // contiguous chunk per wave: sizes 6,6,6,6,6,6,6,7
    const int start = (wv * NBIN) >> 3;
    const int end   = ((wv + 1) * NBIN) >> 3;

    #pragma unroll 2
    for (int bin = start; bin < end; ++bin) {
        const BinInfo bi = sbin[bin];             // 2x ds_read_b128, uniform addr
        const f32x4 f00 = *(const f32x4*)(fbB + (bi.yb0 + bi.xb0 + laneB));
        const f32x4 f01 = *(const f32x4*)(fbB + (bi.yb0 + bi.xb1 + laneB));
        const f32x4 f10 = *(const f32x4*)(fbB + (bi.yb1 + bi.xb0 + laneB));
        const f32x4 f11 = *(const f32x4*)(fbB + (bi.yb1 + bi.xb1 + laneB));
        f32x4 o = bi.w00 * f00 + bi.w01 * f01 + bi.w10 * f10 + bi.w11 * f11;
        // NT store: keep the 51MB write stream from evicting L2-resident features
        __builtin_nontemporal_store(o, (f32x4*)(obB + (((unsigned)bin << 10) + laneB)));
    }
}

extern "C" void kernel_launch(void* const* d_in, const int* in_sizes, int n_in,
                              void* d_out, int out_size, void* d_ws, size_t ws_size,
                              hipStream_t stream) {
    const float* f0    = (const float*)d_in[0];
    const float* f1    = (const float*)d_in[1];
    const float* f2    = (const float*)d_in[2];
    const float* f3    = (const float*)d_in[3];
    const float* f4    = (const float*)d_in[4];
    const float* boxes = (const float*)d_in[5];
    float*       outp  = (float*)d_out;

    roi_pool_kernel<<<B_ * N_, 512, 0, stream>>>(f0, f1, f2, f3, f4, boxes, outp);
}

// Round 7
// 15.384 us; speedup vs baseline: 1.1754x; 1.0409x over previous
//
#include <hip/hip_runtime.h>

#define B_    4
#define N_    256
#define C_    256
#define OUTN  7
#define NBIN  49          // 7x7 bins
#define C4    64          // float4 groups per pixel (1 KiB per pixel)

typedef float f32x4 __attribute__((ext_vector_type(4)));

struct __align__(16) BinInfo {
    float    w00, w01, w10, w11;   // bilinear weights
    unsigned yb0, yb1, xb0, xb1;   // byte offsets: row0/row1, col0/col1
};

// 512 thr/block (8 waves), 1 block/box, 4 blocks/CU = 32 waves/CU.
// lane = c4 channel group; wave wv handles bins wv, wv+8, ... (strided —
// measured best vs contiguous chunks). Everything except the blend
// operands is wave-uniform.
__global__ __launch_bounds__(512) void roi_pool_kernel(
    const float* __restrict__ f0, const float* __restrict__ f1,
    const float* __restrict__ f2, const float* __restrict__ f3,
    const float* __restrict__ f4, const float* __restrict__ boxes,
    float* __restrict__ out)
{
    // ---- XCD-aware block->box swizzle: one batch image per XCD pair ----
    const int i_   = blockIdx.x;
    const int xcd  = i_ & 7;
    const int j_   = i_ >> 3;
    const int bid  = (xcd >> 1) * N_ + (xcd & 1) * 128 + j_;   // b*N + n
    const int b    = bid >> 8;
    const int tid  = threadIdx.x;
    const int lane = tid & 63;
    const int wv   = tid >> 6;

    // ---- per-box scalar params ----
    const float* bx = boxes + (size_t)bid * 4;
    const float y1 = bx[0], x1 = bx[1], y2 = bx[2], x2 = bx[3];
    const float bh = y2 - y1, bw = x2 - x1;
    const float area_sqrt = sqrtf(bh * bw);
    const float lvf = floorf(logf(area_sqrt / 224.0f) / logf(2.0f)) + 4.0f;
    int levels = (int)lvf;
    levels = min(max(levels, 4), 64);
    const int   lvl    = levels - 4;
    const float scale  = exp2f((float)levels);
    const float stride = exp2f((float)lvl);
    const float bnd    = 128.0f / stride - 1.0f;
    const float box_y  = y1 / scale - 0.5f;
    const float box_x  = x1 / scale - 0.5f;
    const float bh_s   = bh / scale;
    const float bw_s   = bw / scale;

    // ---- feature level (jnp gather clamps level index to [0,4]) ----
    const int lg = lvl > 4 ? 4 : lvl;
    const float* feat; int fs;
    switch (lg) {
        case 0:  feat = f0; fs = 128; break;
        case 1:  feat = f1; fs = 64;  break;
        case 2:  feat = f2; fs = 32;  break;
        case 3:  feat = f3; fs = 16;  break;
        default: feat = f4; fs = 8;   break;
    }

    // ---- per-bin params: 4 weights + 4 byte offsets, staged in LDS ----
    __shared__ BinInfo sbin[NBIN];
    if (tid < NBIN) {
        const int oy = tid / 7;
        const int ox = tid - oy * 7;
        const float gy = box_y + (((float)oy + 0.5f) * (1.0f / 7.0f)) * bh_s;
        const float gx = box_x + (((float)ox + 0.5f) * (1.0f / 7.0f)) * bw_s;
        const float py = fmaxf(0.0f, floorf(gy));
        const float px = fmaxf(0.0f, floorf(gx));
        const float ly = gy - py, lx = gx - px;   // may be <0/>1 at edges (ref semantics)
        const float hy = 1.0f - ly, hx = 1.0f - lx;
        const int y0  = (int)fminf(py,        bnd);
        const int y1i = (int)fminf(py + 1.0f, bnd);
        const int x0  = (int)fminf(px,        bnd);
        const int x1i = (int)fminf(px + 1.0f, bnd);
        BinInfo bi;
        bi.w00 = hy * hx; bi.w01 = hy * lx;
        bi.w10 = ly * hx; bi.w11 = ly * lx;
        bi.yb0 = (unsigned)(y0  * fs) << 10;      // row byte offset (fs px * 1KiB)
        bi.yb1 = (unsigned)(y1i * fs) << 10;
        bi.xb0 = (unsigned)x0 << 10;              // col byte offset
        bi.xb1 = (unsigned)x1i << 10;
        sbin[tid] = bi;
    }
    __syncthreads();

    // uniform 64-bit bases; all per-corner addressing is 32-bit offsets
    const char* fbB  = (const char*)feat + (size_t)b * fs * fs * 1024;
    char*       obB  = (char*)out + (size_t)bid * (NBIN * 1024);
    const unsigned laneB = (unsigned)lane << 4;

    #pragma unroll 2
    for (int bin = wv; bin < NBIN; bin += 8) {
        const BinInfo bi = sbin[bin];             // 2x ds_read_b128, uniform addr
        const f32x4 f00 = *(const f32x4*)(fbB + (bi.yb0 + bi.xb0 + laneB));
        const f32x4 f01 = *(const f32x4*)(fbB + (bi.yb0 + bi.xb1 + laneB));
        const f32x4 f10 = *(const f32x4*)(fbB + (bi.yb1 + bi.xb0 + laneB));
        const f32x4 f11 = *(const f32x4*)(fbB + (bi.yb1 + bi.xb1 + laneB));
        f32x4 o = bi.w00 * f00 + bi.w01 * f01 + bi.w10 * f10 + bi.w11 * f11;
        // NT store: keep the 51MB write stream from evicting L2-resident features
        __builtin_nontemporal_store(o, (f32x4*)(obB + (((unsigned)bin << 10) + laneB)));
    }
}

extern "C" void kernel_launch(void* const* d_in, const int* in_sizes, int n_in,
                              void* d_out, int out_size, void* d_ws, size_t ws_size,
                              hipStream_t stream) {
    const float* f0    = (const float*)d_in[0];
    const float* f1    = (const float*)d_in[1];
    const float* f2    = (const float*)d_in[2];
    const float* f3    = (const float*)d_in[3];
    const float* f4    = (const float*)d_in[4];
    const float* boxes = (const float*)d_in[5];
    float*       outp  = (float*)d_out;

    roi_pool_kernel<<<B_ * N_, 512, 0, stream>>>(f0, f1, f2, f3, f4, boxes, outp);
}